// Round 3
// baseline (719.817 us; speedup 1.0000x reference)
//
#include <hip/hip_runtime.h>

#define NPTS   8192
#define NSPLIT 4
#define DSTLEN (NPTS / NSPLIT)     // 2048 dst points per split
#define NGRP   512                 // src groups of 16 points
#define NBLK   (NGRP * NSPLIT)     // 2048 blocks
#define NT     256
#define STEPS  (DSTLEN / 64)       // 32 inner steps per lane
#define MAXIT  20
#define TOLER  1e-3

typedef unsigned long long u64;
typedef unsigned int u32;

// ---- ws byte-offset layout (total ~697 KB) ----
#define WS_BP      0            // float4[8192]        131072 B
#define WS_PART    131072       // double[512][16]      65536 B
#define WS_MINS    196608       // u64[8192][NSPLIT]   262144 B
#define WS_SCAL    458752       // double[13]             104 B
#define WS_FLAGS   458856       // int[22]                 88 B
#define WS_GCNT    458944       // int[MAXIT][NGRP]     40960 B
#define WS_SRC     499904       // float[2][NPTS*3]    196608 B

__device__ inline double atom_ld(const double* p) {
  return __hip_atomic_load(p, __ATOMIC_RELAXED, __HIP_MEMORY_SCOPE_AGENT);
}
__device__ inline void atom_st(double* p, double v) {
  __hip_atomic_store(p, v, __ATOMIC_RELAXED, __HIP_MEMORY_SCOPE_AGENT);
}
__device__ inline u64 atom_ld64(const u64* p) {
  return __hip_atomic_load(p, __ATOMIC_RELAXED, __HIP_MEMORY_SCOPE_AGENT);
}
__device__ inline void atom_st64(u64* p, u64 v) {
  __hip_atomic_store(p, v, __ATOMIC_RELAXED, __HIP_MEMORY_SCOPE_AGENT);
}
__device__ inline float atom_ldf(const float* p) {
  return __hip_atomic_load(p, __ATOMIC_RELAXED, __HIP_MEMORY_SCOPE_AGENT);
}
__device__ inline void atom_stf(float* p, float v) {
  __hip_atomic_store(p, v, __ATOMIC_RELAXED, __HIP_MEMORY_SCOPE_AGENT);
}

// Kabsch rotation from 3x3 cross-covariance H (double, single-thread):
// H = U S V^T (numpy convention), R = V' U^T with last V column flipped if
// det(V U^T) < 0 — matches the reference's Vt-last-row flip exactly.
__device__ void kabsch_R(const double H[3][3], double R[3][3])
{
  double K[3][3]; // H^T H = V S^2 V^T
  for (int i = 0; i < 3; ++i)
    for (int j = 0; j < 3; ++j) {
      double s = 0.0;
      for (int k = 0; k < 3; ++k) s += H[k][i] * H[k][j];
      K[i][j] = s;
    }
  double V[3][3] = {{1,0,0},{0,1,0},{0,0,1}};
  for (int sweep = 0; sweep < 30; ++sweep) {
    double off = K[0][1]*K[0][1] + K[0][2]*K[0][2] + K[1][2]*K[1][2];
    double dia = K[0][0]*K[0][0] + K[1][1]*K[1][1] + K[2][2]*K[2][2];
    if (off <= 1e-28 * (dia + 1e-300)) break;
    for (int pi = 0; pi < 3; ++pi) {
      const int p = (pi == 2) ? 1 : 0;
      const int q = (pi == 0) ? 1 : 2;
      double apq = K[p][q];
      if (fabs(apq) < 1e-300) continue;
      double theta = (K[q][q] - K[p][p]) / (2.0 * apq);
      double t = ((theta >= 0.0) ? 1.0 : -1.0) / (fabs(theta) + sqrt(1.0 + theta*theta));
      double c = 1.0 / sqrt(1.0 + t*t);
      double s = t * c;
      double kpp = K[p][p], kqq = K[q][q];
      K[p][p] = kpp - t * apq;
      K[q][q] = kqq + t * apq;
      K[p][q] = 0.0; K[q][p] = 0.0;
      const int r = 3 - p - q;
      double krp = K[r][p], krq = K[r][q];
      K[r][p] = c*krp - s*krq; K[p][r] = K[r][p];
      K[r][q] = s*krp + c*krq; K[q][r] = K[r][q];
      for (int k = 0; k < 3; ++k) {
        double vkp = V[k][p], vkq = V[k][q];
        V[k][p] = c*vkp - s*vkq;
        V[k][q] = s*vkp + c*vkq;
      }
    }
  }
  double w[3] = {K[0][0], K[1][1], K[2][2]};
  for (int a = 0; a < 2; ++a)          // sort descending (numpy sv order)
    for (int b = 0; b < 2 - a; ++b)
      if (w[b] < w[b+1]) {
        double tw = w[b]; w[b] = w[b+1]; w[b+1] = tw;
        for (int k = 0; k < 3; ++k) { double tv = V[k][b]; V[k][b] = V[k][b+1]; V[k][b+1] = tv; }
      }
  double U[3][3]; // columns u_k = normalize(H v_k)
  for (int k = 0; k < 3; ++k) {
    double u0 = H[0][0]*V[0][k] + H[0][1]*V[1][k] + H[0][2]*V[2][k];
    double u1 = H[1][0]*V[0][k] + H[1][1]*V[1][k] + H[1][2]*V[2][k];
    double u2 = H[2][0]*V[0][k] + H[2][1]*V[1][k] + H[2][2]*V[2][k];
    double n = sqrt(u0*u0 + u1*u1 + u2*u2);
    if (n > 1e-150) { u0 /= n; u1 /= n; u2 /= n; }
    else if (k == 2) { // degenerate smallest sv: complete basis
      u0 = U[1][0]*U[2][1] - U[2][0]*U[1][1];
      u1 = U[2][0]*U[0][1] - U[0][0]*U[2][1];
      u2 = U[0][0]*U[1][1] - U[1][0]*U[0][1];
      double n2 = sqrt(u0*u0 + u1*u1 + u2*u2) + 1e-300;
      u0 /= n2; u1 /= n2; u2 /= n2;
    } else {
      u0 = (k == 0) ? 1.0 : 0.0; u1 = (k == 1) ? 1.0 : 0.0; u2 = 0.0;
    }
    U[0][k] = u0; U[1][k] = u1; U[2][k] = u2;
  }
  double R0[3][3]; // V U^T
  for (int i = 0; i < 3; ++i)
    for (int j = 0; j < 3; ++j)
      R0[i][j] = V[i][0]*U[j][0] + V[i][1]*U[j][1] + V[i][2]*U[j][2];
  double det = R0[0][0]*(R0[1][1]*R0[2][2] - R0[1][2]*R0[2][1])
             - R0[0][1]*(R0[1][0]*R0[2][2] - R0[1][2]*R0[2][0])
             + R0[0][2]*(R0[1][0]*R0[2][1] - R0[1][1]*R0[2][0]);
  if (det < 0.0)
    for (int i = 0; i < 3; ++i)
      for (int j = 0; j < 3; ++j)
        R0[i][j] -= 2.0 * V[i][2] * U[j][2]; // flip last column of V
  for (int i = 0; i < 3; ++i)
    for (int j = 0; j < 3; ++j)
      R[i][j] = R0[i][j];
}

// grid 32 x 256 = 8192 threads: precompute Bp, zero counters/flags
__global__ void icp_init(const float* __restrict__ B, char* __restrict__ ws)
{
  int t = blockIdx.x * NT + threadIdx.x; // 0..8191
  float bx = B[3*t], by = B[3*t+1], bz = B[3*t+2];
  ((float4*)(ws + WS_BP))[t] =
      make_float4(2.f*bx, 2.f*by, 2.f*bz, bx*bx + by*by + bz*bz);
  int* gcnt = (int*)(ws + WS_GCNT);
  gcnt[t] = 0;
  if (t < MAXIT * NGRP - NPTS) gcnt[NPTS + t] = 0; // 10240 total
  if (t == 0) {
    double* scal = (double*)(ws + WS_SCAL);
    int* flags = (int*)(ws + WS_FLAGS);
    scal[0] = 0.0;   // prev_err
    flags[0] = 0;    // done
    flags[1] = -1;   // T_iter
    for (int i = 0; i < MAXIT; ++i) flags[2 + i] = 0; // global election counters
  }
}

// block = group g (16 src points) x split s (2048-dst window)
__global__ __launch_bounds__(NT, 6)
void icp_iter(const float* __restrict__ A, const float* __restrict__ B,
              char* __restrict__ ws, int it)
{
  const float4* __restrict__ Bp = (const float4*)(ws + WS_BP);
  double* partials = (double*)(ws + WS_PART);
  u64*    wsmins   = (u64*)(ws + WS_MINS);
  double* scal     = (double*)(ws + WS_SCAL);
  int*    flags    = (int*)(ws + WS_FLAGS);
  int*    gcnt     = (int*)(ws + WS_GCNT);
  float*  srcW     = (float*)(ws + WS_SRC);

  __shared__ double red1[16 * 16];
  __shared__ double red2[4 * 16];
  __shared__ int lastg, winner;

  const int tid  = threadIdx.x;
  const int blk  = blockIdx.x;
  const int g    = blk >> 2;       // src group
  const int s    = blk & 3;        // dst split
  const int wav  = tid >> 6;
  const int lane = tid & 63;
  const int qbase = g * 16 + wav * 4; // this wave's 4 src points

  int done = 0, titer = -1;
  if (it > 0) { done = flags[0]; titer = flags[1]; }
  const bool app = (it > 0) && (titer == it - 1);
  const float* rbuf = (it == 0) ? A : (srcW + (it & 1) * 3 * NPTS);
  float*       wbuf = srcW + ((it & 1) ^ 1) * 3 * NPTS;
  const bool iwrite = (s == 0);

  if (done && !iwrite) return;

  float sx[4], sy[4], sz[4];
  #pragma unroll
  for (int i = 0; i < 4; ++i) {
    int p = qbase + i;
    sx[i] = rbuf[3*p]; sy[i] = rbuf[3*p+1]; sz[i] = rbuf[3*p+2];
  }
  if (app) { // apply pending T in fp32 (ref: new_src = T @ src in fp32)
    float r00=(float)scal[1], r01=(float)scal[2], r02=(float)scal[3];
    float r10=(float)scal[4], r11=(float)scal[5], r12=(float)scal[6];
    float r20=(float)scal[7], r21=(float)scal[8], r22=(float)scal[9];
    float t0 =(float)scal[10], t1=(float)scal[11], t2=(float)scal[12];
    #pragma unroll
    for (int i = 0; i < 4; ++i) {
      float nx = r00*sx[i] + r01*sy[i] + r02*sz[i] + t0;
      float ny = r10*sx[i] + r11*sy[i] + r12*sz[i] + t1;
      float nz = r20*sx[i] + r21*sy[i] + r22*sz[i] + t2;
      sx[i]=nx; sy[i]=ny; sz[i]=nz;
    }
  }
  if (iwrite) { // split 0 persists (copy-forward when done&&!app)
    #pragma unroll
    for (int i = 0; i < 4; ++i) {
      if (lane == i) {
        int p = qbase + i;
        atom_stf(&wbuf[3*p], sx[i]); atom_stf(&wbuf[3*p+1], sy[i]);
        atom_stf(&wbuf[3*p+2], sz[i]);
      }
    }
  }
  if (done) return;

  // ---- NN scan over this split's 2048-dst window, straight from L2 ----
  float emin[4]; int imin[4];
  #pragma unroll
  for (int i = 0; i < 4; ++i) { emin[i] = 3.4e38f; imin[i] = 0; }
  int jg = s * DSTLEN + lane;
  #pragma unroll 4
  for (int stp = 0; stp < STEPS; ++stp) {
    float4 d = Bp[jg];
    #pragma unroll
    for (int i = 0; i < 4; ++i) {
      // e = |b|^2 - 2 s.b ; argmin_j e == argmin_j d2 (d2 = e + |s|^2)
      float e = fmaf(-sx[i], d.x, fmaf(-sy[i], d.y, fmaf(-sz[i], d.z, d.w)));
      if (e < emin[i]) { emin[i] = e; imin[i] = jg; } // strict < => first index
    }
    jg += 64;
  }
  // wave argmin butterfly (lowest index wins ties)
  #pragma unroll
  for (int m = 1; m < 64; m <<= 1) {
    #pragma unroll
    for (int i = 0; i < 4; ++i) {
      float eo = __shfl_xor(emin[i], m, 64);
      int   io = __shfl_xor(imin[i], m, 64);
      if (eo < emin[i] || (eo == emin[i] && io < imin[i])) { emin[i] = eo; imin[i] = io; }
    }
  }
  // leaders publish packed (monotone(e) << 32) | idx — u64 min == (min e, min idx)
  #pragma unroll
  for (int i = 0; i < 4; ++i) {
    if (lane == i) {
      u32 eb = __float_as_uint(emin[i]);
      u32 key = (eb & 0x80000000u) ? ~eb : (eb | 0x80000000u);
      atom_st64(&wsmins[(u64)(qbase + i) * NSPLIT + s],
                ((u64)key << 32) | (u32)imin[i]);
    }
  }
  __threadfence();      // release mins (+ split0's wbuf) at agent scope
  __syncthreads();
  if (tid == 0) lastg = (atomicAdd(&gcnt[it * NGRP + g], 1) == NSPLIT - 1);
  __syncthreads();
  if (!lastg) return;
  __threadfence();      // acquire partner splits' mins + split0's wbuf

  // ---- last split of group: merge 4 windows, build 16-component partials ----
  if (tid < 16) {
    int p = g * 16 + tid;
    u64 m = atom_ld64(&wsmins[(u64)p * NSPLIT]);
    #pragma unroll
    for (int s2i = 1; s2i < NSPLIT; ++s2i) {
      u64 o = atom_ld64(&wsmins[(u64)p * NSPLIT + s2i]);
      if (o < m) m = o;
    }
    int idx = (int)(m & 0xffffffffu);
    u32 key = (u32)(m >> 32);
    u32 eb = (key & 0x80000000u) ? (key ^ 0x80000000u) : ~key;
    float e = __uint_as_float(eb);
    float x = atom_ldf(&wbuf[3*p]), y = atom_ldf(&wbuf[3*p+1]),
          z = atom_ldf(&wbuf[3*p+2]);
    float s2v = x*x + y*y + z*z;
    float d2 = e + s2v;
    float dist = sqrtf(fmaxf(d2, 0.f) + 1e-12f);
    float bx = B[3*idx], by = B[3*idx+1], bz = B[3*idx+2];
    double* r = red1 + tid * 16;
    r[0]=x; r[1]=y; r[2]=z;
    r[3]=bx; r[4]=by; r[5]=bz;
    r[6]=(double)x*bx; r[7]=(double)x*by; r[8]=(double)x*bz;
    r[9]=(double)y*bx; r[10]=(double)y*by; r[11]=(double)y*bz;
    r[12]=(double)z*bx; r[13]=(double)z*by; r[14]=(double)z*bz;
    r[15]=dist;
  }
  __syncthreads();
  if (tid < 16) {
    double ssum = 0.0;
    for (int q = 0; q < 16; ++q) ssum += red1[q * 16 + tid];
    atom_st(&partials[(size_t)g * 16 + tid], ssum);
  }
  __threadfence();
  __syncthreads();
  if (tid == 0) winner = (atomicAdd(&flags[2 + it], 1) == NGRP - 1);
  __syncthreads();
  if (!winner) return;
  __threadfence();

  // ---- global winner: reduce 512 group-partials, solve, publish T ----
  double a2[16];
  #pragma unroll
  for (int k = 0; k < 16; ++k)
    a2[k] = atom_ld(&partials[(size_t)tid*16 + k]) +
            atom_ld(&partials[(size_t)(tid+256)*16 + k]);
  for (int m = 1; m < 64; m <<= 1) {
    #pragma unroll
    for (int k = 0; k < 16; ++k) a2[k] += __shfl_xor(a2[k], m, 64);
  }
  if (lane == 0)
    for (int k = 0; k < 16; ++k) red2[wav * 16 + k] = a2[k];
  __syncthreads();
  if (tid == 0) {
    double S[16];
    for (int k = 0; k < 16; ++k)
      S[k] = red2[k] + red2[16+k] + red2[32+k] + red2[48+k];
    const double invN = 1.0 / NPTS;
    double cAv[3] = {S[0]*invN, S[1]*invN, S[2]*invN};
    double cBv[3] = {S[3]*invN, S[4]*invN, S[5]*invN};
    double H[3][3];
    for (int i = 0; i < 3; ++i)
      for (int j = 0; j < 3; ++j)
        H[i][j] = S[6 + i*3 + j] - (double)NPTS * cAv[i] * cBv[j];
    double err = S[15] * invN;
    double prev_err = scal[0];
    int conv = (fabs(prev_err - err) < TOLER) ? 1 : 0;
    double R[3][3];
    kabsch_R(H, R);
    double t0 = cBv[0] - (R[0][0]*cAv[0] + R[0][1]*cAv[1] + R[0][2]*cAv[2]);
    double t1 = cBv[1] - (R[1][0]*cAv[0] + R[1][1]*cAv[1] + R[1][2]*cAv[2]);
    double t2 = cBv[2] - (R[2][0]*cAv[0] + R[2][1]*cAv[1] + R[2][2]*cAv[2]);
    scal[1]=R[0][0]; scal[2]=R[0][1]; scal[3]=R[0][2];
    scal[4]=R[1][0]; scal[5]=R[1][1]; scal[6]=R[1][2];
    scal[7]=R[2][0]; scal[8]=R[2][1]; scal[9]=R[2][2];
    scal[10]=t0; scal[11]=t1; scal[12]=t2;
    scal[0]=err;
    flags[0] = conv;   // done latch (only written while !done)
    flags[1] = it;     // T pending application
  }
}

__global__ __launch_bounds__(NT)
void icp_final(const float* __restrict__ A, char* __restrict__ ws,
               float* __restrict__ out)
{
  double* scal = (double*)(ws + WS_SCAL);
  int* flags = (int*)(ws + WS_FLAGS);
  // iter MAXIT-1 (odd) last wrote buffer 0
  const float* sb = (float*)(ws + WS_SRC) + ((((MAXIT - 1) & 1) ^ 1) * 3 * NPTS);
  __shared__ double redf[4][15];

  const int tid = threadIdx.x;
  const int wav = tid >> 6;
  const int lane = tid & 63;

  const bool app = (flags[1] == MAXIT - 1); // T from it=19 never applied
  float r00=(float)scal[1], r01=(float)scal[2], r02=(float)scal[3];
  float r10=(float)scal[4], r11=(float)scal[5], r12=(float)scal[6];
  float r20=(float)scal[7], r21=(float)scal[8], r22=(float)scal[9];
  float t0 =(float)scal[10], t1=(float)scal[11], t2=(float)scal[12];

  double s[15];
  #pragma unroll
  for (int k = 0; k < 15; ++k) s[k] = 0.0;
  for (int p = tid; p < NPTS; p += NT) {
    float ax = A[3*p], ay = A[3*p+1], az = A[3*p+2];
    float x = sb[3*p], y = sb[3*p+1], z = sb[3*p+2];
    if (app) {
      float nx = r00*x + r01*y + r02*z + t0;
      float ny = r10*x + r11*y + r12*z + t1;
      float nz = r20*x + r21*y + r22*z + t2;
      x = nx; y = ny; z = nz;
    }
    s[0]+=ax; s[1]+=ay; s[2]+=az; s[3]+=x; s[4]+=y; s[5]+=z;
    s[6]+=(double)ax*x;  s[7]+=(double)ax*y;  s[8]+=(double)ax*z;
    s[9]+=(double)ay*x;  s[10]+=(double)ay*y; s[11]+=(double)ay*z;
    s[12]+=(double)az*x; s[13]+=(double)az*y; s[14]+=(double)az*z;
  }
  for (int m = 1; m < 64; m <<= 1) {
    #pragma unroll
    for (int k = 0; k < 15; ++k) s[k] += __shfl_xor(s[k], m, 64);
  }
  if (lane == 0)
    for (int k = 0; k < 15; ++k) redf[wav][k] = s[k];
  __syncthreads();
  if (tid == 0) {
    double S[15];
    for (int k = 0; k < 15; ++k)
      S[k] = redf[0][k] + redf[1][k] + redf[2][k] + redf[3][k];
    const double invN = 1.0 / NPTS;
    double cAv[3] = {S[0]*invN, S[1]*invN, S[2]*invN};
    double cSv[3] = {S[3]*invN, S[4]*invN, S[5]*invN};
    double H[3][3];
    for (int i = 0; i < 3; ++i)
      for (int j = 0; j < 3; ++j)
        H[i][j] = S[6 + i*3 + j] - (double)NPTS * cAv[i] * cSv[j];
    double R[3][3];
    kabsch_R(H, R);
    double u0 = cSv[0] - (R[0][0]*cAv[0] + R[0][1]*cAv[1] + R[0][2]*cAv[2]);
    double u1 = cSv[1] - (R[1][0]*cAv[0] + R[1][1]*cAv[1] + R[1][2]*cAv[2]);
    double u2 = cSv[2] - (R[2][0]*cAv[0] + R[2][1]*cAv[1] + R[2][2]*cAv[2]);
    out[0]=(float)R[0][0]; out[1]=(float)R[0][1]; out[2]=(float)R[0][2]; out[3]=(float)u0;
    out[4]=(float)R[1][0]; out[5]=(float)R[1][1]; out[6]=(float)R[1][2]; out[7]=(float)u1;
    out[8]=(float)R[2][0]; out[9]=(float)R[2][1]; out[10]=(float)R[2][2]; out[11]=(float)u2;
    out[12]=0.f; out[13]=0.f; out[14]=0.f; out[15]=1.f;
  }
}

extern "C" void kernel_launch(void* const* d_in, const int* in_sizes, int n_in,
                              void* d_out, int out_size, void* d_ws, size_t ws_size,
                              hipStream_t stream) {
  const float* A = (const float*)d_in[0];
  const float* B = (const float*)d_in[1];
  float* out = (float*)d_out;
  char* ws = (char*)d_ws; // needs ~697 KB

  hipLaunchKernelGGL(icp_init, dim3(NPTS / NT), dim3(NT), 0, stream, B, ws);
  for (int it = 0; it < MAXIT; ++it)
    hipLaunchKernelGGL(icp_iter, dim3(NBLK), dim3(NT), 0, stream, A, B, ws, it);
  hipLaunchKernelGGL(icp_final, dim3(1), dim3(NT), 0, stream, A, ws, out);
}

// Round 5
// 207.783 us; speedup vs baseline: 3.4643x; 3.4643x over previous
//
#include <hip/hip_runtime.h>

#define NPTS   8192
#define NB     256          // one block per CU; each block owns 32 src points
#define NT     256
#define CHUNK  4096         // dst points staged in LDS per pass (64 KB)
#define NCHUNK (NPTS / CHUNK)
#define CSTEPS (CHUNK / 64) // 64 inner steps per chunk per lane
#define MAXIT  20
#define TOLER  1e-3

typedef unsigned long long u64;
typedef unsigned int u32;

// ---- ws byte-offset layout (~257 KB) ----
#define WS_BP      0            // float4[8192]  (2bx,2by,2bz,|b|^2)  131072 B
#define WS_PART    131072       // double[NB][16]                      32768 B
#define WS_SCAL    163840       // double[13]: prev_err, T(12)           104 B
#define WS_FLAGS   163944       // int[22]: done, T_iter, counters[20]    88 B
#define WS_SRC     164032       // float[NPTS*3]                       98304 B

__device__ inline double atom_ld(const double* p) {
  return __hip_atomic_load(p, __ATOMIC_RELAXED, __HIP_MEMORY_SCOPE_AGENT);
}
__device__ inline void atom_st(double* p, double v) {
  __hip_atomic_store(p, v, __ATOMIC_RELAXED, __HIP_MEMORY_SCOPE_AGENT);
}

// Kabsch rotation from 3x3 cross-covariance H (double, single-thread):
// H = U S V^T (numpy convention), R = V' U^T with last V column flipped if
// det(V U^T) < 0 — matches the reference's Vt-last-row flip exactly.
__device__ void kabsch_R(const double H[3][3], double R[3][3])
{
  double K[3][3]; // H^T H = V S^2 V^T
  for (int i = 0; i < 3; ++i)
    for (int j = 0; j < 3; ++j) {
      double s = 0.0;
      for (int k = 0; k < 3; ++k) s += H[k][i] * H[k][j];
      K[i][j] = s;
    }
  double V[3][3] = {{1,0,0},{0,1,0},{0,0,1}};
  for (int sweep = 0; sweep < 30; ++sweep) {
    double off = K[0][1]*K[0][1] + K[0][2]*K[0][2] + K[1][2]*K[1][2];
    double dia = K[0][0]*K[0][0] + K[1][1]*K[1][1] + K[2][2]*K[2][2];
    if (off <= 1e-28 * (dia + 1e-300)) break;
    for (int pi = 0; pi < 3; ++pi) {
      const int p = (pi == 2) ? 1 : 0;
      const int q = (pi == 0) ? 1 : 2;
      double apq = K[p][q];
      if (fabs(apq) < 1e-300) continue;
      double theta = (K[q][q] - K[p][p]) / (2.0 * apq);
      double t = ((theta >= 0.0) ? 1.0 : -1.0) / (fabs(theta) + sqrt(1.0 + theta*theta));
      double c = 1.0 / sqrt(1.0 + t*t);
      double s = t * c;
      double kpp = K[p][p], kqq = K[q][q];
      K[p][p] = kpp - t * apq;
      K[q][q] = kqq + t * apq;
      K[p][q] = 0.0; K[q][p] = 0.0;
      const int r = 3 - p - q;
      double krp = K[r][p], krq = K[r][q];
      K[r][p] = c*krp - s*krq; K[p][r] = K[r][p];
      K[r][q] = s*krp + c*krq; K[q][r] = K[r][q];
      for (int k = 0; k < 3; ++k) {
        double vkp = V[k][p], vkq = V[k][q];
        V[k][p] = c*vkp - s*vkq;
        V[k][q] = s*vkp + c*vkq;
      }
    }
  }
  double w[3] = {K[0][0], K[1][1], K[2][2]};
  for (int a = 0; a < 2; ++a)          // sort descending (numpy sv order)
    for (int b = 0; b < 2 - a; ++b)
      if (w[b] < w[b+1]) {
        double tw = w[b]; w[b] = w[b+1]; w[b+1] = tw;
        for (int k = 0; k < 3; ++k) { double tv = V[k][b]; V[k][b] = V[k][b+1]; V[k][b+1] = tv; }
      }
  double U[3][3]; // columns u_k = normalize(H v_k)
  for (int k = 0; k < 3; ++k) {
    double u0 = H[0][0]*V[0][k] + H[0][1]*V[1][k] + H[0][2]*V[2][k];
    double u1 = H[1][0]*V[0][k] + H[1][1]*V[1][k] + H[1][2]*V[2][k];
    double u2 = H[2][0]*V[0][k] + H[2][1]*V[1][k] + H[2][2]*V[2][k];
    double n = sqrt(u0*u0 + u1*u1 + u2*u2);
    if (n > 1e-150) { u0 /= n; u1 /= n; u2 /= n; }
    else if (k == 2) { // degenerate smallest sv: complete basis
      u0 = U[1][0]*U[2][1] - U[2][0]*U[1][1];
      u1 = U[2][0]*U[0][1] - U[0][0]*U[2][1];
      u2 = U[0][0]*U[1][1] - U[1][0]*U[0][1];
      double n2 = sqrt(u0*u0 + u1*u1 + u2*u2) + 1e-300;
      u0 /= n2; u1 /= n2; u2 /= n2;
    } else {
      u0 = (k == 0) ? 1.0 : 0.0; u1 = (k == 1) ? 1.0 : 0.0; u2 = 0.0;
    }
    U[0][k] = u0; U[1][k] = u1; U[2][k] = u2;
  }
  double R0[3][3]; // V U^T
  for (int i = 0; i < 3; ++i)
    for (int j = 0; j < 3; ++j)
      R0[i][j] = V[i][0]*U[j][0] + V[i][1]*U[j][1] + V[i][2]*U[j][2];
  double det = R0[0][0]*(R0[1][1]*R0[2][2] - R0[1][2]*R0[2][1])
             - R0[0][1]*(R0[1][0]*R0[2][2] - R0[1][2]*R0[2][0])
             + R0[0][2]*(R0[1][0]*R0[2][1] - R0[1][1]*R0[2][0]);
  if (det < 0.0)
    for (int i = 0; i < 3; ++i)
      for (int j = 0; j < 3; ++j)
        R0[i][j] -= 2.0 * V[i][2] * U[j][2]; // flip last column of V
  for (int i = 0; i < 3; ++i)
    for (int j = 0; j < 3; ++j)
      R[i][j] = R0[i][j];
}

// 32 x 256 = 8192 threads: precompute Bp, zero flags/counters
__global__ void icp_init(const float* __restrict__ B, char* __restrict__ ws)
{
  int t = blockIdx.x * NT + threadIdx.x; // 0..8191
  float bx = B[3*t], by = B[3*t+1], bz = B[3*t+2];
  ((float4*)(ws + WS_BP))[t] =
      make_float4(2.f*bx, 2.f*by, 2.f*bz, bx*bx + by*by + bz*bz);
  if (t == 0) {
    double* scal = (double*)(ws + WS_SCAL);
    int* flags = (int*)(ws + WS_FLAGS);
    scal[0] = 0.0;   // prev_err
    flags[0] = 0;    // done
    flags[1] = -1;   // T_iter
    for (int i = 0; i < MAXIT; ++i) flags[2 + i] = 0; // election counters
  }
}

// block b owns src points b*32 .. b*32+31; wave w owns 8 of them.
__global__ __launch_bounds__(NT)
void icp_iter(const float* __restrict__ A, const float* __restrict__ B,
              char* __restrict__ ws, int it)
{
  const float4* __restrict__ Bp = (const float4*)(ws + WS_BP);
  double* partials = (double*)(ws + WS_PART);
  double* scal     = (double*)(ws + WS_SCAL);
  int*    flags    = (int*)(ws + WS_FLAGS);
  float*  srcbuf   = (float*)(ws + WS_SRC);

  __shared__ __align__(16) unsigned char smem[CHUNK * 16]; // 64 KB
  float4* bp_lds = (float4*)smem;                 // NN staging
  double* red1   = (double*)smem;                 // [32][16] leader rows
  double* red2   = (double*)(smem + 32*16*8);     // [4][16] wave sums
  __shared__ int winner_s;

  const int tid  = threadIdx.x;
  const int blk  = blockIdx.x;
  const int wav  = tid >> 6;
  const int lane = tid & 63;
  const int qbase = blk * 32 + wav * 8; // this wave's 8 src points

  int done = 0, titer = -1;
  if (it > 0) { done = flags[0]; titer = flags[1]; }
  const bool app = (it > 0) && (titer == it - 1); // previous iter's T pending
  if (done && !app) return; // srcbuf already holds final state

  float sx[8], sy[8], sz[8];
  const float* rbuf = (it == 0) ? A : srcbuf;
  #pragma unroll
  for (int i = 0; i < 8; ++i) { // broadcast loads: all lanes hold all 8 src
    int p = qbase + i;
    sx[i] = rbuf[3*p]; sy[i] = rbuf[3*p+1]; sz[i] = rbuf[3*p+2];
  }
  if (app) { // apply pending T in fp32 (ref: new_src = T @ src in fp32)
    float r00=(float)scal[1], r01=(float)scal[2], r02=(float)scal[3];
    float r10=(float)scal[4], r11=(float)scal[5], r12=(float)scal[6];
    float r20=(float)scal[7], r21=(float)scal[8], r22=(float)scal[9];
    float t0 =(float)scal[10], t1=(float)scal[11], t2=(float)scal[12];
    #pragma unroll
    for (int i = 0; i < 8; ++i) {
      float nx = r00*sx[i] + r01*sy[i] + r02*sz[i] + t0;
      float ny = r10*sx[i] + r11*sy[i] + r12*sz[i] + t1;
      float nz = r20*sx[i] + r21*sy[i] + r22*sz[i] + t2;
      sx[i]=nx; sy[i]=ny; sz[i]=nz;
    }
  }
  // ALWAYS persist current src (round-4 bug: this was inside `if (app)`,
  // so it=0 never wrote A into srcbuf and it=1 read poison). Each point is
  // written by exactly one lane of one wave; only this block re-reads it.
  #pragma unroll
  for (int i = 0; i < 8; ++i) {
    if (lane == i) {
      int p = qbase + i;
      srcbuf[3*p] = sx[i]; srcbuf[3*p+1] = sy[i]; srcbuf[3*p+2] = sz[i];
    }
  }
  if (done) return; // converging iteration's T applied; state frozen

  // ---- brute-force 1-NN: LDS-staged dst, 8 src per LDS read ----
  float emin[8]; int imin[8];
  #pragma unroll
  for (int i = 0; i < 8; ++i) { emin[i] = 3.4e38f; imin[i] = 0; }

  for (int c = 0; c < NCHUNK; ++c) {
    __syncthreads();
    for (int i = tid; i < CHUNK; i += NT)   // pure float4 copy from L2-hot Bp
      bp_lds[i] = Bp[c * CHUNK + i];
    __syncthreads();
    const int jbase = c * CHUNK + lane;
    #pragma unroll 8
    for (int stp = 0; stp < CSTEPS; ++stp) {
      float4 d = bp_lds[stp * 64 + lane];
      int jg = jbase + stp * 64;
      #pragma unroll
      for (int i = 0; i < 8; ++i) {
        // e = |b|^2 - 2 s.b ; argmin_j e == argmin_j d2 (d2 = e + |s|^2)
        float e = fmaf(-sx[i], d.x, fmaf(-sy[i], d.y, fmaf(-sz[i], d.z, d.w)));
        if (e < emin[i]) { emin[i] = e; imin[i] = jg; } // strict < => first idx
      }
    }
  }
  // wave argmin butterfly (lowest index wins ties)
  #pragma unroll
  for (int m = 1; m < 64; m <<= 1) {
    #pragma unroll
    for (int i = 0; i < 8; ++i) {
      float eo = __shfl_xor(emin[i], m, 64);
      int   io = __shfl_xor(imin[i], m, 64);
      if (eo < emin[i] || (eo == emin[i] && io < imin[i])) { emin[i] = eo; imin[i] = io; }
    }
  }

  __syncthreads(); // all bp_lds reads done before LDS reuse as red1
  #pragma unroll
  for (int i = 0; i < 8; ++i) {
    if (lane == i) { // leader lane i handles src point qbase+i
      float s2 = sx[i]*sx[i] + sy[i]*sy[i] + sz[i]*sz[i];
      float d2 = emin[i] + s2;
      float dist = sqrtf(fmaxf(d2, 0.f) + 1e-12f);
      int j = imin[i];
      float bx = B[3*j], by = B[3*j+1], bz = B[3*j+2];
      double* r = red1 + (wav * 8 + i) * 16;
      r[0]=sx[i]; r[1]=sy[i]; r[2]=sz[i];
      r[3]=bx;    r[4]=by;    r[5]=bz;
      r[6]=(double)sx[i]*bx;  r[7]=(double)sx[i]*by;  r[8]=(double)sx[i]*bz;
      r[9]=(double)sy[i]*bx;  r[10]=(double)sy[i]*by; r[11]=(double)sy[i]*bz;
      r[12]=(double)sz[i]*bx; r[13]=(double)sz[i]*by; r[14]=(double)sz[i]*bz;
      r[15]=dist;
    }
  }
  __syncthreads();
  if (tid < 16) {
    double ssum = 0.0;
    for (int g = 0; g < 32; ++g) ssum += red1[g * 16 + tid];
    atom_st(&partials[(size_t)blk * 16 + tid], ssum);
  }
  __threadfence();      // release partials (agent scope) before election
  __syncthreads();
  if (tid == 0) winner_s = (atomicAdd(&flags[2 + it], 1) == NB - 1);
  __syncthreads();
  if (!winner_s) return;
  __threadfence();      // acquire: all other blocks' partials now visible

  // ---- winner block: reduce 256 partials, solve, publish T ----
  double a2[16];
  #pragma unroll
  for (int k = 0; k < 16; ++k)
    a2[k] = atom_ld(&partials[(size_t)tid * 16 + k]); // one row per thread
  for (int m = 1; m < 64; m <<= 1) {
    #pragma unroll
    for (int k = 0; k < 16; ++k) a2[k] += __shfl_xor(a2[k], m, 64);
  }
  if (lane == 0)
    for (int k = 0; k < 16; ++k) red2[wav * 16 + k] = a2[k];
  __syncthreads();
  if (tid == 0) {
    double S[16];
    for (int k = 0; k < 16; ++k)
      S[k] = red2[k] + red2[16+k] + red2[32+k] + red2[48+k];
    const double invN = 1.0 / NPTS;
    double cAv[3] = {S[0]*invN, S[1]*invN, S[2]*invN};
    double cBv[3] = {S[3]*invN, S[4]*invN, S[5]*invN};
    double H[3][3];
    for (int i = 0; i < 3; ++i)
      for (int j = 0; j < 3; ++j)
        H[i][j] = S[6 + i*3 + j] - (double)NPTS * cAv[i] * cBv[j];
    double err = S[15] * invN;
    double prev_err = scal[0];
    int conv = (fabs(prev_err - err) < TOLER) ? 1 : 0;
    double R[3][3];
    kabsch_R(H, R);
    double t0 = cBv[0] - (R[0][0]*cAv[0] + R[0][1]*cAv[1] + R[0][2]*cAv[2]);
    double t1 = cBv[1] - (R[1][0]*cAv[0] + R[1][1]*cAv[1] + R[1][2]*cAv[2]);
    double t2 = cBv[2] - (R[2][0]*cAv[0] + R[2][1]*cAv[1] + R[2][2]*cAv[2]);
    scal[1]=R[0][0]; scal[2]=R[0][1]; scal[3]=R[0][2];
    scal[4]=R[1][0]; scal[5]=R[1][1]; scal[6]=R[1][2];
    scal[7]=R[2][0]; scal[8]=R[2][1]; scal[9]=R[2][2];
    scal[10]=t0; scal[11]=t1; scal[12]=t2;
    scal[0]=err;
    flags[0] = conv;   // done latch
    flags[1] = it;     // this T pending application
  }
}

__global__ __launch_bounds__(NT)
void icp_final(const float* __restrict__ A, char* __restrict__ ws,
               float* __restrict__ out)
{
  double* scal = (double*)(ws + WS_SCAL);
  int* flags = (int*)(ws + WS_FLAGS);
  const float* sb = (const float*)(ws + WS_SRC);
  __shared__ double redf[4][15];

  const int tid = threadIdx.x;
  const int wav = tid >> 6;
  const int lane = tid & 63;

  const bool app = (flags[1] == MAXIT - 1); // T from it=19 never applied
  float r00=(float)scal[1], r01=(float)scal[2], r02=(float)scal[3];
  float r10=(float)scal[4], r11=(float)scal[5], r12=(float)scal[6];
  float r20=(float)scal[7], r21=(float)scal[8], r22=(float)scal[9];
  float t0 =(float)scal[10], t1=(float)scal[11], t2=(float)scal[12];

  double s[15];
  #pragma unroll
  for (int k = 0; k < 15; ++k) s[k] = 0.0;
  for (int p = tid; p < NPTS; p += NT) {
    float ax = A[3*p], ay = A[3*p+1], az = A[3*p+2];
    float x = sb[3*p], y = sb[3*p+1], z = sb[3*p+2];
    if (app) {
      float nx = r00*x + r01*y + r02*z + t0;
      float ny = r10*x + r11*y + r12*z + t1;
      float nz = r20*x + r21*y + r22*z + t2;
      x = nx; y = ny; z = nz;
    }
    s[0]+=ax; s[1]+=ay; s[2]+=az; s[3]+=x; s[4]+=y; s[5]+=z;
    s[6]+=(double)ax*x;  s[7]+=(double)ax*y;  s[8]+=(double)ax*z;
    s[9]+=(double)ay*x;  s[10]+=(double)ay*y; s[11]+=(double)ay*z;
    s[12]+=(double)az*x; s[13]+=(double)az*y; s[14]+=(double)az*z;
  }
  for (int m = 1; m < 64; m <<= 1) {
    #pragma unroll
    for (int k = 0; k < 15; ++k) s[k] += __shfl_xor(s[k], m, 64);
  }
  if (lane == 0)
    for (int k = 0; k < 15; ++k) redf[wav][k] = s[k];
  __syncthreads();
  if (tid == 0) {
    double S[15];
    for (int k = 0; k < 15; ++k)
      S[k] = redf[0][k] + redf[1][k] + redf[2][k] + redf[3][k];
    const double invN = 1.0 / NPTS;
    double cAv[3] = {S[0]*invN, S[1]*invN, S[2]*invN};
    double cSv[3] = {S[3]*invN, S[4]*invN, S[5]*invN};
    double H[3][3];
    for (int i = 0; i < 3; ++i)
      for (int j = 0; j < 3; ++j)
        H[i][j] = S[6 + i*3 + j] - (double)NPTS * cAv[i] * cSv[j];
    double R[3][3];
    kabsch_R(H, R);
    double u0 = cSv[0] - (R[0][0]*cAv[0] + R[0][1]*cAv[1] + R[0][2]*cAv[2]);
    double u1 = cSv[1] - (R[1][0]*cAv[0] + R[1][1]*cAv[1] + R[1][2]*cAv[2]);
    double u2 = cSv[2] - (R[2][0]*cAv[0] + R[2][1]*cAv[1] + R[2][2]*cAv[2]);
    out[0]=(float)R[0][0]; out[1]=(float)R[0][1]; out[2]=(float)R[0][2]; out[3]=(float)u0;
    out[4]=(float)R[1][0]; out[5]=(float)R[1][1]; out[6]=(float)R[1][2]; out[7]=(float)u1;
    out[8]=(float)R[2][0]; out[9]=(float)R[2][1]; out[10]=(float)R[2][2]; out[11]=(float)u2;
    out[12]=0.f; out[13]=0.f; out[14]=0.f; out[15]=1.f;
  }
}

extern "C" void kernel_launch(void* const* d_in, const int* in_sizes, int n_in,
                              void* d_out, int out_size, void* d_ws, size_t ws_size,
                              hipStream_t stream) {
  const float* A = (const float*)d_in[0];
  const float* B = (const float*)d_in[1];
  float* out = (float*)d_out;
  char* ws = (char*)d_ws; // needs ~257 KB

  hipLaunchKernelGGL(icp_init, dim3(NPTS / NT), dim3(NT), 0, stream, B, ws);
  for (int it = 0; it < MAXIT; ++it)
    hipLaunchKernelGGL(icp_iter, dim3(NB), dim3(NT), 0, stream, A, B, ws, it);
  hipLaunchKernelGGL(icp_final, dim3(1), dim3(NT), 0, stream, A, ws, out);
}